// Round 2
// baseline (194.227 us; speedup 1.0000x reference)
//
#include <hip/hip_runtime.h>

// Conv2d 3x3, cin=4, cout=4, pad=1, stride=1 on [4,4096,4096] fp32.
//
// Round-2 structure: one block per output ROW (512 threads x 8 px = 4096 px).
// Each thread: 8 consecutive output x for ALL 4 cout -> 32 accumulators,
// 1152 FMAs. Interior halos come from __shfl of neighbor lanes (they already
// hold the value in registers); wave-edge lanes do a 1-lane fix-up load;
// image edge is the zero pad. Latency-hiding: 32 indep FMA chains per thread,
// 2 aligned float4 loads per (cin,row).

#define IW 4096
#define IH 4096
constexpr long long HWsz = (long long)IH * IW;

__global__ __launch_bounds__(512) void conv3x3_kernel(
    const float* __restrict__ xin,   // [4][4096][4096]
    const float* __restrict__ wt,    // [4][4][3][3]
    float* __restrict__ out)         // [4][4096][4096]
{
    // one block per row; XCD-bijective swizzle (4096 % 8 == 0):
    // each XCD gets 512 consecutive rows -> 3-row reuse window stays in L2.
    const int cpx = IH >> 3;
    const int bid = blockIdx.x;
    const int y   = (bid & 7) * cpx + (bid >> 3);

    const int tid  = threadIdx.x;
    const int lane = tid & 63;
    const int x0   = tid << 3;          // 8 px per thread, 16B-aligned

    float acc[4][8];
    #pragma unroll
    for (int co = 0; co < 4; ++co)
        #pragma unroll
        for (int xo = 0; xo < 8; ++xo) acc[co][xo] = 0.f;

    #pragma unroll
    for (int ci = 0; ci < 4; ++ci) {
        const float* plane = xin + ci * HWsz;
        #pragma unroll
        for (int r = 0; r < 3; ++r) {
            const int yy = y + r - 1;
            float vals[10];
            if (yy >= 0 && yy < IH) {            // wave-uniform branch
                const float* rowp = plane + (long long)yy * IW;
                const float4 a = *reinterpret_cast<const float4*>(rowp + x0);
                const float4 b = *reinterpret_cast<const float4*>(rowp + x0 + 4);
                vals[1] = a.x; vals[2] = a.y; vals[3] = a.z; vals[4] = a.w;
                vals[5] = b.x; vals[6] = b.y; vals[7] = b.z; vals[8] = b.w;
                // halos: neighbor lane already holds them in registers
                float left  = __shfl_up(b.w, 1);   // lane i-1's x0+7 == my x0-1
                float right = __shfl_down(a.x, 1); // lane i+1's x0   == my x0+8
                if (lane == 0)                      // cross-wave / image edge
                    left  = (tid == 0)   ? 0.f : rowp[x0 - 1];
                if (lane == 63)
                    right = (tid == 511) ? 0.f : rowp[x0 + 8];
                vals[0] = left; vals[9] = right;
            } else {
                #pragma unroll
                for (int t = 0; t < 10; ++t) vals[t] = 0.f;
            }
            #pragma unroll
            for (int co = 0; co < 4; ++co) {
                #pragma unroll
                for (int kx = 0; kx < 3; ++kx) {
                    // uniform address -> scalar-cache load, hoisted
                    const float w = wt[((co * 4 + ci) * 3 + r) * 3 + kx];
                    #pragma unroll
                    for (int xo = 0; xo < 8; ++xo)
                        acc[co][xo] = fmaf(w, vals[xo + kx], acc[co][xo]);
                }
            }
        }
    }

    const long long obase = (long long)y * IW + x0;
    #pragma unroll
    for (int co = 0; co < 4; ++co) {
        float4 o0, o1;
        o0.x = acc[co][0]; o0.y = acc[co][1]; o0.z = acc[co][2]; o0.w = acc[co][3];
        o1.x = acc[co][4]; o1.y = acc[co][5]; o1.z = acc[co][6]; o1.w = acc[co][7];
        *reinterpret_cast<float4*>(out + co * HWsz + obase)     = o0;
        *reinterpret_cast<float4*>(out + co * HWsz + obase + 4) = o1;
    }
}

extern "C" void kernel_launch(void* const* d_in, const int* in_sizes, int n_in,
                              void* d_out, int out_size, void* d_ws, size_t ws_size,
                              hipStream_t stream) {
    const float* xin = (const float*)d_in[0];
    const float* wt  = (const float*)d_in[1];
    float* out       = (float*)d_out;

    dim3 grid(4096), block(512);
    hipLaunchKernelGGL(conv3x3_kernel, grid, block, 0, stream, xin, wt, out);
}

// Round 3
// 153.652 us; speedup vs baseline: 1.2641x; 1.2641x over previous
//
#include <hip/hip_runtime.h>

// Conv2d 3x3, cin=4, cout=4, pad=1, stride=1 on [4,4096,4096] fp32.
//
// Round-3: register vertical reuse. One thread = 4 px (x) x 4 rows (y) x
// 4 cout = 64 accumulators, 2304 FMAs. Per cin it streams 6 input rows
// (y0-1 .. y0+4); each row is loaded once (1 float4 + 2 L1-hit halo scalars)
// and feeds up to 3 output rows (up to 144 FMAs per load group). FMA/load = 32.
// Block = 256 threads covers 1024 px x 4 rows. Grid = 4 x-blocks x 1024
// row-blocks = 4096, XCD-bijective swizzle -> 512-row band per XCD keeps the
// vertical reuse window in that XCD's L2.

#define IW 4096
#define IH 4096
constexpr long long HWsz = (long long)IH * IW;

__global__ __launch_bounds__(256) void conv3x3_kernel(
    const float* __restrict__ xin,   // [4][4096][4096]
    const float* __restrict__ wt,    // [4][4][3][3]
    float* __restrict__ out)         // [4][4096][4096]
{
    const int nwg = 4096;
    const int cpx = nwg >> 3;                  // 512 blocks per XCD chunk
    const int bid = blockIdx.x;
    const int swz = (bid & 7) * cpx + (bid >> 3);

    const int rowblk = swz >> 2;               // [0, 1024)
    const int xblk   = swz & 3;
    const int y0     = rowblk << 2;            // 4 output rows y0..y0+3
    const int x0     = (xblk * 256 + (int)threadIdx.x) * 4;  // 16B aligned

    float acc[4][4][4];                        // [orow][cout][px]
    #pragma unroll
    for (int o = 0; o < 4; ++o)
        #pragma unroll
        for (int co = 0; co < 4; ++co)
            #pragma unroll
            for (int p = 0; p < 4; ++p) acc[o][co][p] = 0.f;

    #pragma unroll
    for (int ci = 0; ci < 4; ++ci) {
        const float* plane = xin + ci * HWsz;
        #pragma unroll
        for (int dy = -1; dy <= 4; ++dy) {     // input row y0+dy
            const int yy = y0 + dy;
            float v[6];
            if (yy >= 0 && yy < IH) {          // wave-uniform branch
                const float* rowp = plane + (long long)yy * IW;
                const float4 a = *reinterpret_cast<const float4*>(rowp + x0);
                v[1] = a.x; v[2] = a.y; v[3] = a.z; v[4] = a.w;
                v[0] = (x0 > 0)      ? rowp[x0 - 1] : 0.f;  // same-wave L1 hit
                v[5] = (x0 + 4 < IW) ? rowp[x0 + 4] : 0.f;  // same-wave L1 hit
            } else {
                #pragma unroll
                for (int t = 0; t < 6; ++t) v[t] = 0.f;
            }
            // input row yy feeds output row yo = yy - r + 1 for tap row r
            #pragma unroll
            for (int r = 0; r < 3; ++r) {
                const int yo = dy + 1 - r;     // compile-time after unroll
                if (yo >= 0 && yo < 4) {
                    #pragma unroll
                    for (int co = 0; co < 4; ++co) {
                        #pragma unroll
                        for (int kx = 0; kx < 3; ++kx) {
                            const float w = wt[((co * 4 + ci) * 3 + r) * 3 + kx];
                            #pragma unroll
                            for (int p = 0; p < 4; ++p)
                                acc[yo][co][p] = fmaf(w, v[p + kx], acc[yo][co][p]);
                        }
                    }
                }
            }
        }
    }

    #pragma unroll
    for (int o = 0; o < 4; ++o) {
        const long long obase = (long long)(y0 + o) * IW + x0;
        #pragma unroll
        for (int co = 0; co < 4; ++co) {
            float4 ov;
            ov.x = acc[o][co][0]; ov.y = acc[o][co][1];
            ov.z = acc[o][co][2]; ov.w = acc[o][co][3];
            *reinterpret_cast<float4*>(out + co * HWsz + obase) = ov;
        }
    }
}

extern "C" void kernel_launch(void* const* d_in, const int* in_sizes, int n_in,
                              void* d_out, int out_size, void* d_ws, size_t ws_size,
                              hipStream_t stream) {
    const float* xin = (const float*)d_in[0];
    const float* wt  = (const float*)d_in[1];
    float* out       = (float*)d_out;

    dim3 grid(4096), block(256);
    hipLaunchKernelGGL(conv3x3_kernel, grid, block, 0, stream, xin, wt, out);
}